// Round 1
// baseline (128.980 us; speedup 1.0000x reference)
//
#include <hip/hip_runtime.h>
#include <cstdint>
#include <cstddef>

// Problem constants
#define BB_ 64
#define SS_ 256
#define LL_ 4
#define HH_ 1024

// ws layout (in floats)
#define ZF_OFF   ((size_t)0)                        // [2][64][4][256] = 131072
#define MASK_OFF ((size_t)131072)                   // [2][64][256]    = 32768
#define PA_OFF   ((size_t)163840)                   // [half2][t2][64][4][1024] = 1048576
#define DEN_OFF  ((size_t)1212416)                  // [half2][t2][64][4] = 1024
#define Y_OFF    ((size_t)1214464)                  // [64][64] = 4096
#define FZ_OFF   ((size_t)1218560)                  // [128] ints

// ---------------------------------------------------------------------------
// Main fused kernel: layernorm + score + exp + online pooled accumulation.
// grid = 1024: idx = (t<<9) | (b<<3) | (l<<1) | shalf ; block = 512 (8 waves)
// Each wave owns 16 rows (s values); no barriers inside the s-loop.
// MODE 0: normal pass (assumes mask==1, records all-zero flags).
// MODE 1: fixup pass, early-exit unless this (t,b) has a masked row.
// ---------------------------------------------------------------------------
template <int MODE>
__global__ __launch_bounds__(512) void attn_pool(const float* __restrict__ A_,
                                                 const float* __restrict__ B_,
                                                 const float* __restrict__ P_,
                                                 float* __restrict__ ws) {
  int idx = blockIdx.x;
  int shalf = idx & 1;
  int l = (idx >> 1) & 3;
  int bb = (idx >> 3) & 63;
  int t = idx >> 9;

  if (MODE == 1) {
    const int* fz = reinterpret_cast<const int*>(ws + FZ_OFF);
    if (fz[t * 64 + bb] >= SS_) return;  // mask all-ones for this (t,b): keep pass-0 result
  }

  const float* __restrict__ X = t ? B_ : A_;
  int tid = threadIdx.x;
  int wid = tid >> 6;
  int ln = tid & 63;

  // preload p[b,l,:] in registers, same lane mapping as row loads
  float pv[16];
  {
    const float4* pr = reinterpret_cast<const float4*>(P_ + ((size_t)bb * LL_ + l) * HH_);
#pragma unroll
    for (int k = 0; k < 4; ++k) {
      float4 v = pr[k * 64 + ln];
      pv[4 * k + 0] = v.x; pv[4 * k + 1] = v.y;
      pv[4 * k + 2] = v.z; pv[4 * k + 3] = v.w;
    }
  }

  float acc[16];
#pragma unroll
  for (int j = 0; j < 16; ++j) acc[j] = 0.f;
  float den = 0.f;

  float* zf = ws + ZF_OFF + (((size_t)t * 64 + bb) * 4 + l) * SS_;
  const float* mk = ws + MASK_OFF + ((size_t)t * 64 + bb) * SS_;

  const float* base = X + (((size_t)bb * SS_ + (size_t)shalf * 128) * LL_ + l) * HH_;

  for (int i = 0; i < 16; ++i) {
    int s_local = i * 8 + wid;  // 0..127 within this half
    const float4* row = reinterpret_cast<const float4*>(base + (size_t)s_local * (LL_ * HH_));
    float x[16];
    float s1 = 0.f, s2 = 0.f;
#pragma unroll
    for (int k = 0; k < 4; ++k) {
      float4 v = row[k * 64 + ln];
      x[4 * k + 0] = v.x; x[4 * k + 1] = v.y;
      x[4 * k + 2] = v.z; x[4 * k + 3] = v.w;
      s1 += v.x + v.y + v.z + v.w;
      s2 += v.x * v.x + v.y * v.y + v.z * v.z + v.w * v.w;
    }
#pragma unroll
    for (int off = 32; off > 0; off >>= 1) {
      s1 += __shfl_xor(s1, off);
      s2 += __shfl_xor(s2, off);
    }
    float m = s1 * (1.0f / 1024.0f);
    float var = s2 * (1.0f / 1024.0f) - m * m;
    float rstd = rsqrtf(var + 1e-5f);

    float d = 0.f;
#pragma unroll
    for (int j = 0; j < 16; ++j) {
      x[j] -= m;
      d += x[j] * pv[j];
    }
#pragma unroll
    for (int off = 32; off > 0; off >>= 1) d += __shfl_xor(d, off);

    float e = expf(d * rstd * 0.03125f);  // exp(sa), no max-subtraction (matches ref)
    if (MODE == 0) {
      if (ln == 0) zf[shalf * 128 + s_local] = (s2 == 0.f) ? 1.f : 0.f;
    } else {
      e *= mk[shalf * 128 + s_local];
    }
    float coef = e * rstd;
#pragma unroll
    for (int j = 0; j < 16; ++j) acc[j] += coef * x[j];
    den += e;
  }

  // combine 8 wave-partials via LDS
  __shared__ float sm[8 * 1024];
#pragma unroll
  for (int k = 0; k < 4; ++k) {
#pragma unroll
    for (int j = 0; j < 4; ++j) sm[wid * 1024 + (k * 64 + ln) * 4 + j] = acc[4 * k + j];
  }
  __syncthreads();
  float* pa = ws + PA_OFF + ((((size_t)shalf * 2 + t) * 64 + bb) * 4 + l) * HH_;
  for (int e2 = tid; e2 < 1024; e2 += 512) {
    float tot = 0.f;
#pragma unroll
    for (int w = 0; w < 8; ++w) tot += sm[w * 1024 + e2];
    pa[e2] = tot;
  }
  __syncthreads();
  if (ln == 0) sm[wid] = den;
  __syncthreads();
  if (tid == 0) {
    float dd = 0.f;
#pragma unroll
    for (int w = 0; w < 8; ++w) dd += sm[w];
    ws[DEN_OFF + (((size_t)shalf * 2 + t) * 64 + bb) * 4 + l] = dd;
  }
}

// ---------------------------------------------------------------------------
// Build mask (cumprod of "not all-zero across layers") + first-zero index.
// grid = 128 (t*64+b), block = 256 (one thread per s).
// ---------------------------------------------------------------------------
__global__ __launch_bounds__(256) void mask_kernel(float* __restrict__ ws) {
  int idx = blockIdx.x;
  int t = idx >> 6, bb = idx & 63;
  int s = threadIdx.x;
  const float* zf = ws + ZF_OFF + (((size_t)t * 64 + bb) * 4) * SS_;
  float z0 = zf[0 * SS_ + s], z1 = zf[1 * SS_ + s];
  float z2 = zf[2 * SS_ + s], z3 = zf[3 * SS_ + s];
  bool allzero = (z0 != 0.f) && (z1 != 0.f) && (z2 != 0.f) && (z3 != 0.f);
  int fz = allzero ? s : SS_;
#pragma unroll
  for (int off = 32; off > 0; off >>= 1) fz = min(fz, __shfl_xor(fz, off));
  __shared__ int red[4];
  int wid = s >> 6, ln = s & 63;
  if (ln == 0) red[wid] = fz;
  __syncthreads();
  int fzmin = min(min(red[0], red[1]), min(red[2], red[3]));
  ws[MASK_OFF + ((size_t)t * 64 + bb) * SS_ + s] = (s < fzmin) ? 1.f : 0.f;
  if (s == 0) reinterpret_cast<int*>(ws + FZ_OFF)[t * 64 + bb] = fzmin;
}

// ---------------------------------------------------------------------------
// Head: feat = [p, pa, pb, p*pa, p*pb] ; y[b,l,:] = feat . ffnn_w[l] + b
// grid = 256 (b*4+l), block = 256 (4 h-values each).
// ---------------------------------------------------------------------------
__global__ __launch_bounds__(256) void head_kernel(const float* __restrict__ p,
                                                   const float* __restrict__ fw,
                                                   const float* __restrict__ fb,
                                                   float* __restrict__ ws) {
  int blk = blockIdx.x;
  int bb = blk >> 2, l = blk & 3;
  int t = threadIdx.x;

  const float* den = ws + DEN_OFF;
  float inv_a = 1.0f / (den[((0 * 2 + 0) * 64 + bb) * 4 + l] +
                        den[((1 * 2 + 0) * 64 + bb) * 4 + l] + 1e-15f);
  float inv_b = 1.0f / (den[((0 * 2 + 1) * 64 + bb) * 4 + l] +
                        den[((1 * 2 + 1) * 64 + bb) * 4 + l] + 1e-15f);

  const float4* pa00 = reinterpret_cast<const float4*>(ws + PA_OFF + (((size_t)(0 * 2 + 0) * 64 + bb) * 4 + l) * HH_);
  const float4* pa10 = reinterpret_cast<const float4*>(ws + PA_OFF + (((size_t)(1 * 2 + 0) * 64 + bb) * 4 + l) * HH_);
  const float4* pb01 = reinterpret_cast<const float4*>(ws + PA_OFF + (((size_t)(0 * 2 + 1) * 64 + bb) * 4 + l) * HH_);
  const float4* pb11 = reinterpret_cast<const float4*>(ws + PA_OFF + (((size_t)(1 * 2 + 1) * 64 + bb) * 4 + l) * HH_);

  float4 pv = reinterpret_cast<const float4*>(p + ((size_t)bb * LL_ + l) * HH_)[t];
  float4 A0 = pa00[t], A1 = pa10[t], B0 = pb01[t], B1 = pb11[t];
  float av[4] = {(A0.x + A1.x) * inv_a, (A0.y + A1.y) * inv_a,
                 (A0.z + A1.z) * inv_a, (A0.w + A1.w) * inv_a};
  float bv[4] = {(B0.x + B1.x) * inv_b, (B0.y + B1.y) * inv_b,
                 (B0.z + B1.z) * inv_b, (B0.w + B1.w) * inv_b};
  float cp[4] = {pv.x, pv.y, pv.z, pv.w};

  float part[16];
#pragma unroll
  for (int o = 0; o < 16; ++o) part[o] = 0.f;

  const float* wl = fw + (size_t)l * 5120 * 16;
#pragma unroll
  for (int j = 0; j < 4; ++j) {
    int h = t * 4 + j;
    float c[5] = {cp[j], av[j], bv[j], cp[j] * av[j], cp[j] * bv[j]};
#pragma unroll
    for (int sec = 0; sec < 5; ++sec) {
      const float4* wr = reinterpret_cast<const float4*>(wl + ((size_t)sec * 1024 + h) * 16);
#pragma unroll
      for (int o4 = 0; o4 < 4; ++o4) {
        float4 w4 = wr[o4];
        part[o4 * 4 + 0] += c[sec] * w4.x;
        part[o4 * 4 + 1] += c[sec] * w4.y;
        part[o4 * 4 + 2] += c[sec] * w4.z;
        part[o4 * 4 + 3] += c[sec] * w4.w;
      }
    }
  }

  __shared__ float red[256 * 17 + 16 * 17];
#pragma unroll
  for (int o = 0; o < 16; ++o) red[t * 17 + o] = part[o];
  __syncthreads();
  {
    int o = t & 15, g = t >> 4;
    float sacc = 0.f;
#pragma unroll
    for (int i = 0; i < 16; ++i) sacc += red[(g * 16 + i) * 17 + o];
    red[256 * 17 + g * 17 + o] = sacc;
  }
  __syncthreads();
  if (t < 16) {
    float sacc = 0.f;
#pragma unroll
    for (int g = 0; g < 16; ++g) sacc += red[256 * 17 + g * 17 + t];
    ws[Y_OFF + (size_t)bb * 64 + l * 16 + t] = sacc + fb[l * 16 + t];
  }
}

// ---------------------------------------------------------------------------
// Final: BN(eval)+ReLU, tanh encodings, z @ ms_w + ms_b -> out[64,3]
// grid = 64 (b), block = 64 (one wave, k = feature)
// ---------------------------------------------------------------------------
__global__ __launch_bounds__(64) void out_kernel(
    const float* __restrict__ ap, const float* __restrict__ bp,
    const float* __restrict__ gam, const float* __restrict__ bet,
    const float* __restrict__ rm, const float* __restrict__ rv,
    const float* __restrict__ msw, const float* __restrict__ msb,
    const float* __restrict__ dw, const float* __restrict__ db,
    const float* __restrict__ ws, float* __restrict__ out) {
  int bb = blockIdx.x;
  int k = threadIdx.x;
  float yv = ws[Y_OFF + (size_t)bb * 64 + k];
  yv = (yv - rm[k]) * rsqrtf(rv[k] + 1e-5f) * gam[k] + bet[k];
  yv = fmaxf(yv, 0.f);
  float w0 = dw[0], b0 = db[0];
  float ape = tanhf(ap[bb] * w0 + b0);
  float bpe = tanhf(bp[bb] * w0 + b0);
#pragma unroll
  for (int c = 0; c < 3; ++c) {
    float v = yv * msw[k * 3 + c];
#pragma unroll
    for (int off = 32; off > 0; off >>= 1) v += __shfl_xor(v, off);
    if (k == 0) out[bb * 3 + c] = v + ape * msw[64 * 3 + c] + bpe * msw[65 * 3 + c] + msb[c];
  }
}

extern "C" void kernel_launch(void* const* d_in, const int* in_sizes, int n_in,
                              void* d_out, int out_size, void* d_ws, size_t ws_size,
                              hipStream_t stream) {
  (void)in_sizes; (void)n_in; (void)out_size; (void)ws_size;
  const float* a = (const float*)d_in[0];
  const float* b = (const float*)d_in[1];
  const float* p = (const float*)d_in[2];
  const float* ap = (const float*)d_in[3];
  const float* bp = (const float*)d_in[4];
  const float* ffnn_w = (const float*)d_in[5];
  const float* ffnn_b = (const float*)d_in[6];
  const float* bn_g = (const float*)d_in[7];
  const float* bn_b = (const float*)d_in[8];
  const float* bn_rm = (const float*)d_in[9];
  const float* bn_rv = (const float*)d_in[10];
  const float* ms_w = (const float*)d_in[11];
  const float* ms_b = (const float*)d_in[12];
  const float* dist_w = (const float*)d_in[13];
  const float* dist_b = (const float*)d_in[14];
  float* ws = (float*)d_ws;
  float* out = (float*)d_out;

  hipLaunchKernelGGL((attn_pool<0>), dim3(1024), dim3(512), 0, stream, a, b, p, ws);
  hipLaunchKernelGGL(mask_kernel, dim3(128), dim3(256), 0, stream, ws);
  hipLaunchKernelGGL((attn_pool<1>), dim3(1024), dim3(512), 0, stream, a, b, p, ws);
  hipLaunchKernelGGL(head_kernel, dim3(256), dim3(256), 0, stream, p, ffnn_w, ffnn_b, ws);
  hipLaunchKernelGGL(out_kernel, dim3(64), dim3(64), 0, stream,
                     ap, bp, bn_g, bn_b, bn_rm, bn_rv, ms_w, ms_b, dist_w, dist_b, ws, out);
}